// Round 5
// baseline (68.049 us; speedup 1.0000x reference)
//
#include <hip/hip_runtime.h>

#define NB    2
#define NCAM  6
#define CFEAT 80
#define FH    32
#define FW    88
#define FHW   (FH*FW)          // 2816
#define NPTS  150000
#define BEVN  180
#define NCELL (BEVN*BEVN)      // 32400
#define NWIN  (NB*NCAM*NCELL)  // 388800

#define NREG  586              // ceil(NPTS/256)
#define PBLK  (NB*NREG)        // 1172 project blocks
#define TBLK  (NB*NCAM*44)     // 528 transpose blocks (FHW = 44*64)
#define GRID_PT (PBLK + TBLK)  // 1700

// ---- ws layout ----
#define WIN_BYTE_OFF 4096
#define WIN_BYTES   (NWIN*4)                          // 1,555,200
#define FEATT_OFF   ((size_t)(WIN_BYTE_OFF + WIN_BYTES + 255) & ~(size_t)255)
#define FEATT_BYTES ((size_t)NB*NCAM*FHW*CFEAT*4)     // 10,813,440
#define WS_NEED     (FEATT_OFF + FEATT_BYTES)

__device__ inline void inv3x3(const double m[9], double* o) {
    double c00 = m[4]*m[8] - m[5]*m[7];
    double c01 = m[5]*m[6] - m[3]*m[8];
    double c02 = m[3]*m[7] - m[4]*m[6];
    double det = m[0]*c00 + m[1]*c01 + m[2]*c02;
    double id  = 1.0 / det;
    o[0] = c00 * id;
    o[1] = (m[2]*m[7] - m[1]*m[8]) * id;
    o[2] = (m[1]*m[5] - m[2]*m[4]) * id;
    o[3] = c01 * id;
    o[4] = (m[0]*m[8] - m[2]*m[6]) * id;
    o[5] = (m[2]*m[3] - m[0]*m[5]) * id;
    o[6] = c02 * id;
    o[7] = (m[1]*m[6] - m[0]*m[7]) * id;
    o[8] = (m[0]*m[4] - m[1]*m[3]) * id;
}

__device__ inline void inv3x3f(const float m[9], float* o) {
    float c00 = m[4]*m[8] - m[5]*m[7];
    float c01 = m[5]*m[6] - m[3]*m[8];
    float c02 = m[3]*m[7] - m[4]*m[6];
    float det = m[0]*c00 + m[1]*c01 + m[2]*c02;
    float id  = 1.0f / det;
    o[0] = c00 * id;
    o[1] = (m[2]*m[7] - m[1]*m[8]) * id;
    o[2] = (m[1]*m[5] - m[2]*m[4]) * id;
    o[3] = c01 * id;
    o[4] = (m[0]*m[8] - m[2]*m[6]) * id;
    o[5] = (m[2]*m[3] - m[0]*m[5]) * id;
    o[6] = c02 * id;
    o[7] = (m[1]*m[6] - m[0]*m[7]) * id;
    o[8] = (m[0]*m[4] - m[1]*m[3]) * id;
}

// Conservative f32 frustum filter (proven non-dropping across rounds 3-4):
// margins cover worst-case f32 cancellation (~0.03) with 20x floor.
__device__ inline bool filt(float cv0, float cv1, float cv2, const float* C) {
    float zc = C[0]*cv0 + C[1]*cv1 + C[2]*cv2 + C[3];
    float n0 = C[4]*cv0 + C[5]*cv1 + C[6]*cv2 + C[7];
    float n1 = C[8]*cv0 + C[9]*cv1 + C[10]*cv2 + C[11];
    if (zc >= 1e-3f) {
        float w0 = n0 + (C[12]*zc + C[13]) * zc;
        float w1 = n1 + (C[14]*zc + C[15]) * zc;
        float m0 = 0.5f + 2e-4f * (fabsf(w0) + 704.0f * zc);
        float m1 = 0.5f + 2e-4f * (fabsf(w1) + 256.0f * zc);
        return (w0 > -m0) && (w0 < 704.0f*zc + m0) && (w1 > -m1) && (w1 < 256.0f*zc + m1);
    }
    return (fabsf(n0) < 2.0f) && (fabsf(n1) < 2.0f);
}

// Per-block prep into LDS, spread across lanes 0..13 for shorter serial chains:
//  t==0: f32 invLam; t==1: f64 invLam; t in [2,8): f64 cam coeffs (1 lane/cam);
//  t in [8,14): f32 cam filter consts (1 lane/cam). Bit-identical across blocks.
__device__ void prep_block(int t, int b,
                           const float* __restrict__ l2i,
                           const float* __restrict__ iam,
                           const float* __restrict__ lam,
                           double* __restrict__ sW,    // [0..11] IL, 12+c*33 cams
                           float* __restrict__ sFC,    // 6*16
                           float* __restrict__ sIL) {  // 12
    if (t == 0) {
        const float* Lb = lam + b * 16;
        float m[9];
        for (int i = 0; i < 3; ++i)
            for (int j = 0; j < 3; ++j) m[i*3+j] = Lb[i*4+j];
        inv3x3f(m, sIL);
        for (int i = 0; i < 3; ++i) sIL[9+i] = Lb[i*4+3];
    }
    if (t == 1) {
        const float* Lb = lam + b * 16;
        double m[9];
        for (int i = 0; i < 3; ++i)
            for (int j = 0; j < 3; ++j) m[i*3+j] = (double)Lb[i*4+j];
        inv3x3(m, sW);
        for (int i = 0; i < 3; ++i) sW[9+i] = (double)Lb[i*4+3];
    }
    if (t >= 8 && t < 8 + NCAM) {
        int c = t - 8;
        const float* L = l2i + (b*NCAM + c) * 16;
        const float* A = iam + (b*NCAM + c) * 16;
        float* C = sFC + c * 16;
        C[0]=L[8]; C[1]=L[9]; C[2]=L[10]; C[3]=L[11];
        for (int j = 0; j < 4; ++j) {
            C[4+j] = A[0]*L[j] + A[1]*L[4+j];
            C[8+j] = A[4]*L[j] + A[5]*L[4+j];
        }
        C[12]=A[2]; C[13]=A[3]; C[14]=A[6]; C[15]=A[7];
    }
    if (t >= 2 && t < 2 + NCAM) {
        int c = t - 2;
        const float* L = l2i + (b*NCAM + c) * 16;
        const float* A = iam + (b*NCAM + c) * 16;
        double* K = sW + 12 + c * 33;
        K[0]=(double)L[8]; K[1]=(double)L[9]; K[2]=(double)L[10]; K[3]=(double)L[11];
        for (int j = 0; j < 4; ++j) {
            K[4+j] = (double)A[0]*(double)L[j] + (double)A[1]*(double)L[4+j];
            K[8+j] = (double)A[4]*(double)L[j] + (double)A[5]*(double)L[4+j];
        }
        K[12]=(double)A[2]; K[13]=(double)A[3]; K[14]=(double)A[6]; K[15]=(double)A[7];
        // scale_intrinsics bug replication (cam0 rows 0,2 /8; cam1 rows 1,2 /64)
        double ms[9], ts[3];
        for (int i = 0; i < 3; ++i) {
            double s = 1.0;
            if (c == 0 && (i == 0 || i == 2)) s = 0.125;
            if (c == 1 && (i == 1 || i == 2)) s = 0.015625;
            for (int j = 0; j < 3; ++j) ms[i*3+j] = (double)L[i*4+j] * s;
            ts[i] = (double)L[i*4+3] * s;
        }
        double IM[9];
        inv3x3(ms, IM);
        for (int rw = 0; rw < 3; ++rw) {
            double P0 = IM[rw*3+0] * 0.125;
            double P1 = IM[rw*3+1] * 0.125;
            double I2 = IM[rw*3+2];
            K[16 + rw*5 + 0] = P0;
            K[16 + rw*5 + 1] = P1;
            K[16 + rw*5 + 2] = P0*(double)A[6] + P1*(double)A[2];
            K[16 + rw*5 + 3] = P0*(double)A[7] + P1*(double)A[3] + I2;
            K[16 + rw*5 + 4] = -(IM[rw*3+0]*ts[0] + IM[rw*3+1]*ts[1] + IM[rw*3+2]*ts[2]);
        }
    }
}

// Fused: blocks [0,PBLK) = self-contained filter+project per (b, region);
//        blocks [PBLK,GRID_PT) = feature transpose (b,c,ch,hw)->(b,c,hw,ch).
__global__ void __launch_bounds__(256) pt_kernel(const float* __restrict__ pts,
                                                 const float* __restrict__ feat,
                                                 float* __restrict__ featT,
                                                 const float* __restrict__ l2i,
                                                 const float* __restrict__ iam,
                                                 const float* __restrict__ lam,
                                                 int* __restrict__ win) {
    __shared__ double smem[2600];   // 20800 B, aliased per block role
    int bx = blockIdx.x, t = threadIdx.x;

    if (bx >= PBLK) {
        // ---- transpose ----
        float* tile = (float*)smem;          // 80*65 floats
        int i  = bx - PBLK;
        int bc = i / 44;
        int s0 = (i % 44) * 64;
        int j   = t & 63;
        int ch0 = t >> 6;
        for (int ch = ch0; ch < CFEAT; ch += 4)
            tile[ch * 65 + j] = feat[(bc * CFEAT + ch) * FHW + s0 + j];
        __syncthreads();
        for (int w = t; w < 64 * CFEAT; w += 256) {
            int jj = w / CFEAT, ch = w % CFEAT;
            featT[((size_t)bc * FHW + s0 + jj) * CFEAT + ch] = tile[ch * 65 + jj];
        }
        return;
    }

    // ---- filter + project, fully in-block ----
    double*         sW    = smem;                       // 210 dbl
    float4*         sP    = (float4*)(smem + 210);      // 256 float4 (16B aligned)
    float*          sFC   = (float*)(sP + 256);         // 96 f
    float*          sIL   = sFC + 96;                   // 12 f
    int*            sCnt  = (int*)(sIL + 12);           // 24
    int*            sOff  = sCnt + 24;                  // 24
    int*            sT    = sOff + 24;                  // 1
    unsigned short* sList = (unsigned short*)(sT + 1);  // 1536

    int b = bx / NREG;
    int r = bx - b * NREG;
    int n = r * 256 + t;
    bool ok = (n < NPTS);
    float4 p = make_float4(0.f, 0.f, 0.f, 0.f);
    if (ok) p = ((const float4*)pts)[b * NPTS + n];
    sP[t] = p;
    prep_block(t, b, l2i, iam, lam, sW, sFC, sIL);
    __syncthreads();

    float pm0 = p.x - sIL[9], pm1 = p.y - sIL[10], pm2 = p.z - sIL[11];
    float cv0 = sIL[0]*pm0 + sIL[1]*pm1 + sIL[2]*pm2;
    float cv1 = sIL[3]*pm0 + sIL[4]*pm1 + sIL[5]*pm2;
    float cv2 = sIL[6]*pm0 + sIL[7]*pm1 + sIL[8]*pm2;

    int lane = t & 63, wid = t >> 6;
    unsigned long long bm[NCAM];
#pragma unroll
    for (int c = 0; c < NCAM; ++c) {
        bool pass = ok && filt(cv0, cv1, cv2, sFC + c * 16);
        bm[c] = __ballot(pass);
        if (lane == 0) sCnt[c*4 + wid] = __popcll(bm[c]);
    }
    __syncthreads();
    if (t == 0) {
        int acc = 0;
        for (int c = 0; c < NCAM; ++c)
            for (int w = 0; w < 4; ++w) { sOff[c*4 + w] = acc; acc += sCnt[c*4 + w]; }
        sT[0] = acc;
    }
    __syncthreads();
#pragma unroll
    for (int c = 0; c < NCAM; ++c) {
        if ((bm[c] >> lane) & 1ull) {
            int pos = sOff[c*4 + wid] + __popcll(bm[c] & ((1ull << lane) - 1ull));
            sList[pos] = (unsigned short)((c << 8) | t);
        }
    }
    __syncthreads();

    int T = sT[0];
    for (int e = t; e < T; e += 256) {
        int entry = sList[e];
        int px = entry & 255;
        int c  = entry >> 8;
        float4 q = sP[px];
        const double* IL = sW;
        const double* K  = sW + 12 + c * 33;

        double dm0 = (double)q.x - IL[9];
        double dm1 = (double)q.y - IL[10];
        double dm2 = (double)q.z - IL[11];
        double dv0 = IL[0]*dm0 + IL[1]*dm1 + IL[2]*dm2;
        double dv1 = IL[3]*dm0 + IL[4]*dm1 + IL[5]*dm2;
        double dv2 = IL[6]*dm0 + IL[7]*dm1 + IL[8]*dm2;

        double zc = K[0]*dv0 + K[1]*dv1 + K[2]*dv2 + K[3];
        double d  = fmin(fmax(zc, 1e-5), 1e5);
        double inv_d = 1.0 / d;
        double n0 = K[4]*dv0 + K[5]*dv1 + K[6]*dv2 + K[7];
        double n1 = K[8]*dv0 + K[9]*dv1 + K[10]*dv2 + K[11];
        double c1 = n0 * inv_d + (K[12]*d + K[13]);   // col, [0,704)
        double c0 = n1 * inv_d + (K[14]*d + K[15]);   // row, [0,256)
        if (!((c0 >= 0.0) && (c0 < 256.0) && (c1 >= 0.0) && (c1 < 704.0))) continue;

        double dd = d * d;
        double X = K[16]*n1 + K[17]*n0 + K[18]*dd + K[19]*d + K[20];
        double Y = K[21]*n1 + K[22]*n0 + K[23]*dd + K[24]*d + K[25];
        double Z = K[26]*n1 + K[27]*n0 + K[28]*dd + K[29]*d + K[30];
        double xl = trunc(X);
        double yl = trunc(Y);
        if (!((Z >= 0.0) && (xl >= -54.0) && (yl >= -54.0) && (xl < 54.0) && (yl < 54.0)))
            continue;

        int ui = (int)(c0 * 0.125);
        int vi = (int)(c1 * 0.125);
        int xi = (10 * (int)xl) / 3;   // == trunc(xl/0.3) for integer xl (exact)
        int yi = (10 * (int)yl) / 3;
        if (xi < 0) xi += BEVN;
        if (yi < 0) yi += BEVN;

        int nn = r * 256 + px;
        int packed = (nn << 12) | (ui << 7) | vi;
        int cell = (b*NCAM + c) * NCELL + xi * BEVN + yi;
        // Read-before-RMW: values in win are monotone non-decreasing, so a read
        // can never exceed the true running max -> skipping when cur >= packed
        // is provably safe, and drops ~6x of the device-scope atomics.
        int cur = ((volatile int*)win)[cell];
        if (packed > cur) atomicMax(&win[cell], packed);
    }
}

// Emit from transposed features: 320 threads, 32 cells/block,
// 10 subs/cell, 8 channels/sub as two aligned float4 gathers.
__global__ void __launch_bounds__(320) emit_t_kernel(const float* __restrict__ featT,
                                                     const int* __restrict__ win,
                                                     float* __restrict__ out) {
    __shared__ int   sbase[NCAM][32];
    __shared__ float sacc[CFEAT][33];
    int b = blockIdx.y;
    int cell0 = blockIdx.x * 32;
    int t = threadIdx.x;

    if (t < 32 * NCAM) {
        int c = t >> 5, celli = t & 31;
        int cell = cell0 + celli;
        int base = -1;
        if (cell < NCELL) {
            int w = win[(b * NCAM + c) * NCELL + cell];
            if (w >= 0) {
                int ui = (w >> 7) & 31;
                int vi = w & 127;
                base = ((b * NCAM + c) * FHW + ui * FW + vi) * CFEAT;
            }
        }
        sbase[c][celli] = base;
    }
    __syncthreads();

    int celli = t / 10;          // 0..31
    int sub   = t - celli * 10;  // 0..9 -> 8 channels each
    float acc[8];
#pragma unroll
    for (int k = 0; k < 8; ++k) acc[k] = 0.0f;
    for (int c = 0; c < NCAM; ++c) {
        int base = sbase[c][celli];
        if (base >= 0) {
            const float4* f4 = (const float4*)(featT + base + sub * 8);  // 32B-aligned
            float4 v0 = f4[0], v1 = f4[1];
            acc[0] += v0.x; acc[1] += v0.y; acc[2] += v0.z; acc[3] += v0.w;
            acc[4] += v1.x; acc[5] += v1.y; acc[6] += v1.z; acc[7] += v1.w;
        }
    }
#pragma unroll
    for (int k = 0; k < 8; ++k) sacc[sub * 8 + k][celli] = acc[k];
    __syncthreads();

    for (int w = t; w < 32 * CFEAT; w += 320) {
        int ch = w >> 5, ci = w & 31;
        int cell = cell0 + ci;
        if (cell < NCELL)
            out[(b * CFEAT + ch) * NCELL + cell] = sacc[ch][ci];
    }
}

// Fallback emit from original layout (only if ws can't hold featT).
__global__ void emit_kernel(const float* __restrict__ feat,
                            const int* __restrict__ win,
                            float* __restrict__ out) {
    __shared__ int   sbase[32][NCAM];
    __shared__ float sacc[32][81];
    int b = blockIdx.y;
    int cell0 = blockIdx.x * 32;
    int t = threadIdx.x;

    if (t < 32 * NCAM) {
        int celli = t / NCAM, c = t % NCAM;
        int cell = cell0 + celli;
        int base = -1;
        if (cell < NCELL) {
            int w = win[(b * NCAM + c) * NCELL + cell];
            if (w >= 0) {
                int ui = (w >> 7) & 31;
                int vi = w & 127;
                base = ((b * NCAM + c) * CFEAT) * FHW + ui * FW + vi;
            }
        }
        sbase[celli][c] = base;
    }
    __syncthreads();

    int celli = t & 31;
    int sub   = t >> 5;
    for (int k = 0; k < 10; ++k) {
        int ch = sub * 10 + k;
        float acc = 0.0f;
        for (int c = 0; c < NCAM; ++c) {
            int base = sbase[celli][c];
            if (base >= 0) acc += feat[base + ch * FHW];
        }
        sacc[celli][ch] = acc;
    }
    __syncthreads();

    for (int w = t; w < 32 * CFEAT; w += 256) {
        int ch = w >> 5, ci = w & 31;
        int cell = cell0 + ci;
        if (cell < NCELL)
            out[(b * CFEAT + ch) * NCELL + cell] = sacc[ci][ch];
    }
}

extern "C" void kernel_launch(void* const* d_in, const int* in_sizes, int n_in,
                              void* d_out, int out_size, void* d_ws, size_t ws_size,
                              hipStream_t stream) {
    const float* img_feat = (const float*)d_in[0];
    const float* points   = (const float*)d_in[1];
    const float* l2i      = (const float*)d_in[2];
    const float* iam      = (const float*)d_in[3];
    const float* lam      = (const float*)d_in[4];

    int*   win   = (int*)((char*)d_ws + WIN_BYTE_OFF);
    float* featT = (float*)((char*)d_ws + FEATT_OFF);
    bool use_t = ws_size >= WS_NEED;

    hipMemsetAsync(win, 0xFF, WIN_BYTES, stream);   // all cells -> -1

    hipLaunchKernelGGL(pt_kernel, dim3(use_t ? GRID_PT : PBLK), dim3(256), 0, stream,
                       points, img_feat, featT, l2i, iam, lam, win);

    if (use_t) {
        hipLaunchKernelGGL(emit_t_kernel, dim3((NCELL + 31) / 32, NB), dim3(320), 0,
                           stream, featT, win, (float*)d_out);
    } else {
        hipLaunchKernelGGL(emit_kernel, dim3((NCELL + 31) / 32, NB), dim3(256), 0,
                           stream, img_feat, win, (float*)d_out);
    }
}

// Round 6
// 39.784 us; speedup vs baseline: 1.7105x; 1.7105x over previous
//
#include <hip/hip_runtime.h>

#define NB    2
#define NCAM  6
#define CFEAT 80
#define FH    32
#define FW    88
#define FHW   (FH*FW)          // 2816
#define NPTS  150000
#define BEVN  180
#define NCELL (BEVN*BEVN)      // 32400
#define NWIN  (NB*NCAM*NCELL)  // 388800

#define NREG  586              // ceil(NPTS/256)
#define PBLK  (NB*NREG)        // 1172 project blocks
#define TBLK  (NB*NCAM*44)     // 528 transpose blocks (FHW = 44*64)
#define GRID_PT (PBLK + TBLK)  // 1700

#define WIN_BYTE_OFF 4096
#define FEATT_BYTES ((size_t)NB*NCAM*FHW*CFEAT*4)     // 10,813,440

__device__ inline void inv3x3(const double m[9], double* o) {
    double c00 = m[4]*m[8] - m[5]*m[7];
    double c01 = m[5]*m[6] - m[3]*m[8];
    double c02 = m[3]*m[7] - m[4]*m[6];
    double det = m[0]*c00 + m[1]*c01 + m[2]*c02;
    double id  = 1.0 / det;
    o[0] = c00 * id;
    o[1] = (m[2]*m[7] - m[1]*m[8]) * id;
    o[2] = (m[1]*m[5] - m[2]*m[4]) * id;
    o[3] = c01 * id;
    o[4] = (m[0]*m[8] - m[2]*m[6]) * id;
    o[5] = (m[2]*m[3] - m[0]*m[5]) * id;
    o[6] = c02 * id;
    o[7] = (m[1]*m[6] - m[0]*m[7]) * id;
    o[8] = (m[0]*m[4] - m[1]*m[3]) * id;
}

__device__ inline void inv3x3f(const float m[9], float* o) {
    float c00 = m[4]*m[8] - m[5]*m[7];
    float c01 = m[5]*m[6] - m[3]*m[8];
    float c02 = m[3]*m[7] - m[4]*m[6];
    float det = m[0]*c00 + m[1]*c01 + m[2]*c02;
    float id  = 1.0f / det;
    o[0] = c00 * id;
    o[1] = (m[2]*m[7] - m[1]*m[8]) * id;
    o[2] = (m[1]*m[5] - m[2]*m[4]) * id;
    o[3] = c01 * id;
    o[4] = (m[0]*m[8] - m[2]*m[6]) * id;
    o[5] = (m[2]*m[3] - m[0]*m[5]) * id;
    o[6] = c02 * id;
    o[7] = (m[1]*m[6] - m[0]*m[7]) * id;
    o[8] = (m[0]*m[4] - m[1]*m[3]) * id;
}

// Conservative f32 frustum filter (proven non-dropping across rounds 3-5):
// margins cover worst-case f32 cancellation (~0.03) with 20x floor.
__device__ inline bool filt(float cv0, float cv1, float cv2, const float* C) {
    float zc = C[0]*cv0 + C[1]*cv1 + C[2]*cv2 + C[3];
    float n0 = C[4]*cv0 + C[5]*cv1 + C[6]*cv2 + C[7];
    float n1 = C[8]*cv0 + C[9]*cv1 + C[10]*cv2 + C[11];
    if (zc >= 1e-3f) {
        float w0 = n0 + (C[12]*zc + C[13]) * zc;
        float w1 = n1 + (C[14]*zc + C[15]) * zc;
        float m0 = 0.5f + 2e-4f * (fabsf(w0) + 704.0f * zc);
        float m1 = 0.5f + 2e-4f * (fabsf(w1) + 256.0f * zc);
        return (w0 > -m0) && (w0 < 704.0f*zc + m0) && (w1 > -m1) && (w1 < 256.0f*zc + m1);
    }
    return (fabsf(n0) < 2.0f) && (fabsf(n1) < 2.0f);
}

// Per-block prep into LDS, spread across lanes 0..13. Bit-identical across blocks.
__device__ void prep_block(int t, int b,
                           const float* __restrict__ l2i,
                           const float* __restrict__ iam,
                           const float* __restrict__ lam,
                           double* __restrict__ sW,    // [0..11] IL, 12+c*33 cams
                           float* __restrict__ sFC,    // 6*16
                           float* __restrict__ sIL) {  // 12
    if (t == 0) {
        const float* Lb = lam + b * 16;
        float m[9];
        for (int i = 0; i < 3; ++i)
            for (int j = 0; j < 3; ++j) m[i*3+j] = Lb[i*4+j];
        inv3x3f(m, sIL);
        for (int i = 0; i < 3; ++i) sIL[9+i] = Lb[i*4+3];
    }
    if (t == 1) {
        const float* Lb = lam + b * 16;
        double m[9];
        for (int i = 0; i < 3; ++i)
            for (int j = 0; j < 3; ++j) m[i*3+j] = (double)Lb[i*4+j];
        inv3x3(m, sW);
        for (int i = 0; i < 3; ++i) sW[9+i] = (double)Lb[i*4+3];
    }
    if (t >= 8 && t < 8 + NCAM) {
        int c = t - 8;
        const float* L = l2i + (b*NCAM + c) * 16;
        const float* A = iam + (b*NCAM + c) * 16;
        float* C = sFC + c * 16;
        C[0]=L[8]; C[1]=L[9]; C[2]=L[10]; C[3]=L[11];
        for (int j = 0; j < 4; ++j) {
            C[4+j] = A[0]*L[j] + A[1]*L[4+j];
            C[8+j] = A[4]*L[j] + A[5]*L[4+j];
        }
        C[12]=A[2]; C[13]=A[3]; C[14]=A[6]; C[15]=A[7];
    }
    if (t >= 2 && t < 2 + NCAM) {
        int c = t - 2;
        const float* L = l2i + (b*NCAM + c) * 16;
        const float* A = iam + (b*NCAM + c) * 16;
        double* K = sW + 12 + c * 33;
        K[0]=(double)L[8]; K[1]=(double)L[9]; K[2]=(double)L[10]; K[3]=(double)L[11];
        for (int j = 0; j < 4; ++j) {
            K[4+j] = (double)A[0]*(double)L[j] + (double)A[1]*(double)L[4+j];
            K[8+j] = (double)A[4]*(double)L[j] + (double)A[5]*(double)L[4+j];
        }
        K[12]=(double)A[2]; K[13]=(double)A[3]; K[14]=(double)A[6]; K[15]=(double)A[7];
        // scale_intrinsics bug replication (cam0 rows 0,2 /8; cam1 rows 1,2 /64)
        double ms[9], ts[3];
        for (int i = 0; i < 3; ++i) {
            double s = 1.0;
            if (c == 0 && (i == 0 || i == 2)) s = 0.125;
            if (c == 1 && (i == 1 || i == 2)) s = 0.015625;
            for (int j = 0; j < 3; ++j) ms[i*3+j] = (double)L[i*4+j] * s;
            ts[i] = (double)L[i*4+3] * s;
        }
        double IM[9];
        inv3x3(ms, IM);
        for (int rw = 0; rw < 3; ++rw) {
            double P0 = IM[rw*3+0] * 0.125;
            double P1 = IM[rw*3+1] * 0.125;
            double I2 = IM[rw*3+2];
            K[16 + rw*5 + 0] = P0;
            K[16 + rw*5 + 1] = P1;
            K[16 + rw*5 + 2] = P0*(double)A[6] + P1*(double)A[2];
            K[16 + rw*5 + 3] = P0*(double)A[7] + P1*(double)A[3] + I2;
            K[16 + rw*5 + 4] = -(IM[rw*3+0]*ts[0] + IM[rw*3+1]*ts[1] + IM[rw*3+2]*ts[2]);
        }
    }
}

// Fused: blocks [0,PBLK) = filter+project into win partition (bx & (NPART-1));
//        blocks [PBLK,..) = feature transpose (b,c,ch,hw)->(b,c,hw,ch).
template<int NPART>
__global__ void __launch_bounds__(256) pt_kernel(const float* __restrict__ pts,
                                                 const float* __restrict__ feat,
                                                 float* __restrict__ featT,
                                                 const float* __restrict__ l2i,
                                                 const float* __restrict__ iam,
                                                 const float* __restrict__ lam,
                                                 int* __restrict__ win) {
    __shared__ double smem[2600];   // 20800 B, aliased per block role
    int bx = blockIdx.x, t = threadIdx.x;

    if (bx >= PBLK) {
        // ---- transpose ----
        float* tile = (float*)smem;          // 80*65 floats
        int i  = bx - PBLK;
        int bc = i / 44;
        int s0 = (i % 44) * 64;
        int j   = t & 63;
        int ch0 = t >> 6;
        for (int ch = ch0; ch < CFEAT; ch += 4)
            tile[ch * 65 + j] = feat[(bc * CFEAT + ch) * FHW + s0 + j];
        __syncthreads();
        for (int w = t; w < 64 * CFEAT; w += 256) {
            int jj = w / CFEAT, ch = w % CFEAT;
            featT[((size_t)bc * FHW + s0 + jj) * CFEAT + ch] = tile[ch * 65 + jj];
        }
        return;
    }

    // ---- filter + project, fully in-block ----
    double*         sW    = smem;                       // 210 dbl
    float4*         sP    = (float4*)(smem + 210);      // 256 float4
    float*          sFC   = (float*)(sP + 256);         // 96 f
    float*          sIL   = sFC + 96;                   // 12 f
    int*            sCnt  = (int*)(sIL + 12);           // 24
    int*            sOff  = sCnt + 24;                  // 24
    int*            sT    = sOff + 24;                  // 1
    unsigned short* sList = (unsigned short*)(sT + 1);  // 1536

    // Partition by likely-XCD (dispatch round-robins workgroups over 8 XCDs):
    // each partition's win lines are touched (mostly) by one XCD -> no
    // cross-XCD line migration on the atomic stream.
    int* winp = win + (bx & (NPART - 1)) * NWIN;

    int b = bx / NREG;
    int r = bx - b * NREG;
    int n = r * 256 + t;
    bool ok = (n < NPTS);
    float4 p = make_float4(0.f, 0.f, 0.f, 0.f);
    if (ok) p = ((const float4*)pts)[b * NPTS + n];
    sP[t] = p;
    prep_block(t, b, l2i, iam, lam, sW, sFC, sIL);
    __syncthreads();

    float pm0 = p.x - sIL[9], pm1 = p.y - sIL[10], pm2 = p.z - sIL[11];
    float cv0 = sIL[0]*pm0 + sIL[1]*pm1 + sIL[2]*pm2;
    float cv1 = sIL[3]*pm0 + sIL[4]*pm1 + sIL[5]*pm2;
    float cv2 = sIL[6]*pm0 + sIL[7]*pm1 + sIL[8]*pm2;

    int lane = t & 63, wid = t >> 6;
    unsigned long long bm[NCAM];
#pragma unroll
    for (int c = 0; c < NCAM; ++c) {
        bool pass = ok && filt(cv0, cv1, cv2, sFC + c * 16);
        bm[c] = __ballot(pass);
        if (lane == 0) sCnt[c*4 + wid] = __popcll(bm[c]);
    }
    __syncthreads();
    if (t == 0) {
        int acc = 0;
        for (int c = 0; c < NCAM; ++c)
            for (int w = 0; w < 4; ++w) { sOff[c*4 + w] = acc; acc += sCnt[c*4 + w]; }
        sT[0] = acc;
    }
    __syncthreads();
#pragma unroll
    for (int c = 0; c < NCAM; ++c) {
        if ((bm[c] >> lane) & 1ull) {
            int pos = sOff[c*4 + wid] + __popcll(bm[c] & ((1ull << lane) - 1ull));
            sList[pos] = (unsigned short)((c << 8) | t);
        }
    }
    __syncthreads();

    int T = sT[0];
    for (int e = t; e < T; e += 256) {
        int entry = sList[e];
        int px = entry & 255;
        int c  = entry >> 8;
        float4 q = sP[px];
        const double* IL = sW;
        const double* K  = sW + 12 + c * 33;

        double dm0 = (double)q.x - IL[9];
        double dm1 = (double)q.y - IL[10];
        double dm2 = (double)q.z - IL[11];
        double dv0 = IL[0]*dm0 + IL[1]*dm1 + IL[2]*dm2;
        double dv1 = IL[3]*dm0 + IL[4]*dm1 + IL[5]*dm2;
        double dv2 = IL[6]*dm0 + IL[7]*dm1 + IL[8]*dm2;

        double zc = K[0]*dv0 + K[1]*dv1 + K[2]*dv2 + K[3];
        double d  = fmin(fmax(zc, 1e-5), 1e5);
        double inv_d = 1.0 / d;
        double n0 = K[4]*dv0 + K[5]*dv1 + K[6]*dv2 + K[7];
        double n1 = K[8]*dv0 + K[9]*dv1 + K[10]*dv2 + K[11];
        double c1 = n0 * inv_d + (K[12]*d + K[13]);   // col, [0,704)
        double c0 = n1 * inv_d + (K[14]*d + K[15]);   // row, [0,256)
        if (!((c0 >= 0.0) && (c0 < 256.0) && (c1 >= 0.0) && (c1 < 704.0))) continue;

        double dd = d * d;
        double X = K[16]*n1 + K[17]*n0 + K[18]*dd + K[19]*d + K[20];
        double Y = K[21]*n1 + K[22]*n0 + K[23]*dd + K[24]*d + K[25];
        double Z = K[26]*n1 + K[27]*n0 + K[28]*dd + K[29]*d + K[30];
        double xl = trunc(X);
        double yl = trunc(Y);
        if (!((Z >= 0.0) && (xl >= -54.0) && (yl >= -54.0) && (xl < 54.0) && (yl < 54.0)))
            continue;

        int ui = (int)(c0 * 0.125);
        int vi = (int)(c1 * 0.125);
        int xi = (10 * (int)xl) / 3;   // == trunc(xl/0.3) for integer xl (exact)
        int yi = (10 * (int)yl) / 3;
        if (xi < 0) xi += BEVN;
        if (yi < 0) yi += BEVN;

        int nn = r * 256 + px;
        int packed = (nn << 12) | (ui << 7) | vi;
        // fire-and-forget device atomic into the XCD-local partition
        atomicMax(&winp[(b*NCAM + c) * NCELL + xi * BEVN + yi], packed);
    }
}

// Emit: max-merge the NPART win partitions, gather channel-last features.
template<int NPART>
__global__ void __launch_bounds__(320) emit_t_kernel(const float* __restrict__ featT,
                                                     const int* __restrict__ win,
                                                     float* __restrict__ out) {
    __shared__ int   sbase[NCAM][32];
    __shared__ float sacc[CFEAT][33];
    int b = blockIdx.y;
    int cell0 = blockIdx.x * 32;
    int t = threadIdx.x;

    if (t < 32 * NCAM) {
        int c = t >> 5, celli = t & 31;
        int cell = cell0 + celli;
        int base = -1;
        if (cell < NCELL) {
            int idx = (b * NCAM + c) * NCELL + cell;
            int w = win[idx];
#pragma unroll
            for (int p = 1; p < NPART; ++p)
                w = max(w, win[p * NWIN + idx]);
            if (w >= 0) {
                int ui = (w >> 7) & 31;
                int vi = w & 127;
                base = ((b * NCAM + c) * FHW + ui * FW + vi) * CFEAT;
            }
        }
        sbase[c][celli] = base;
    }
    __syncthreads();

    int celli = t / 10;          // 0..31
    int sub   = t - celli * 10;  // 0..9 -> 8 channels each
    float acc[8];
#pragma unroll
    for (int k = 0; k < 8; ++k) acc[k] = 0.0f;
    for (int c = 0; c < NCAM; ++c) {
        int base = sbase[c][celli];
        if (base >= 0) {
            const float4* f4 = (const float4*)(featT + base + sub * 8);  // 32B-aligned
            float4 v0 = f4[0], v1 = f4[1];
            acc[0] += v0.x; acc[1] += v0.y; acc[2] += v0.z; acc[3] += v0.w;
            acc[4] += v1.x; acc[5] += v1.y; acc[6] += v1.z; acc[7] += v1.w;
        }
    }
#pragma unroll
    for (int k = 0; k < 8; ++k) sacc[sub * 8 + k][celli] = acc[k];
    __syncthreads();

    for (int w = t; w < 32 * CFEAT; w += 320) {
        int ch = w >> 5, ci = w & 31;
        int cell = cell0 + ci;
        if (cell < NCELL)
            out[(b * CFEAT + ch) * NCELL + cell] = sacc[ch][ci];
    }
}

// Fallback emit from original layout (only if ws can't hold featT).
__global__ void emit_kernel(const float* __restrict__ feat,
                            const int* __restrict__ win,
                            float* __restrict__ out) {
    __shared__ int   sbase[32][NCAM];
    __shared__ float sacc[32][81];
    int b = blockIdx.y;
    int cell0 = blockIdx.x * 32;
    int t = threadIdx.x;

    if (t < 32 * NCAM) {
        int celli = t / NCAM, c = t % NCAM;
        int cell = cell0 + celli;
        int base = -1;
        if (cell < NCELL) {
            int w = win[(b * NCAM + c) * NCELL + cell];
            if (w >= 0) {
                int ui = (w >> 7) & 31;
                int vi = w & 127;
                base = ((b * NCAM + c) * CFEAT) * FHW + ui * FW + vi;
            }
        }
        sbase[celli][c] = base;
    }
    __syncthreads();

    int celli = t & 31;
    int sub   = t >> 5;
    for (int k = 0; k < 10; ++k) {
        int ch = sub * 10 + k;
        float acc = 0.0f;
        for (int c = 0; c < NCAM; ++c) {
            int base = sbase[celli][c];
            if (base >= 0) acc += feat[base + ch * FHW];
        }
        sacc[celli][ch] = acc;
    }
    __syncthreads();

    for (int w = t; w < 32 * CFEAT; w += 256) {
        int ch = w >> 5, ci = w & 31;
        int cell = cell0 + ci;
        if (cell < NCELL)
            out[(b * CFEAT + ch) * NCELL + cell] = sacc[ci][ch];
    }
}

extern "C" void kernel_launch(void* const* d_in, const int* in_sizes, int n_in,
                              void* d_out, int out_size, void* d_ws, size_t ws_size,
                              hipStream_t stream) {
    const float* img_feat = (const float*)d_in[0];
    const float* points   = (const float*)d_in[1];
    const float* l2i      = (const float*)d_in[2];
    const float* iam      = (const float*)d_in[3];
    const float* lam      = (const float*)d_in[4];

    int* win = (int*)((char*)d_ws + WIN_BYTE_OFF);

    size_t win8   = (size_t)NWIN * 4 * 8;
    size_t foff8  = (WIN_BYTE_OFF + win8 + 255) & ~(size_t)255;
    size_t win1   = (size_t)NWIN * 4;
    size_t foff1  = (WIN_BYTE_OFF + win1 + 255) & ~(size_t)255;

    if (ws_size >= foff8 + FEATT_BYTES) {
        float* featT = (float*)((char*)d_ws + foff8);
        hipMemsetAsync(win, 0xFF, win8, stream);
        hipLaunchKernelGGL((pt_kernel<8>), dim3(GRID_PT), dim3(256), 0, stream,
                           points, img_feat, featT, l2i, iam, lam, win);
        hipLaunchKernelGGL((emit_t_kernel<8>), dim3((NCELL + 31) / 32, NB), dim3(320), 0,
                           stream, featT, win, (float*)d_out);
    } else if (ws_size >= foff1 + FEATT_BYTES) {
        float* featT = (float*)((char*)d_ws + foff1);
        hipMemsetAsync(win, 0xFF, win1, stream);
        hipLaunchKernelGGL((pt_kernel<1>), dim3(GRID_PT), dim3(256), 0, stream,
                           points, img_feat, featT, l2i, iam, lam, win);
        hipLaunchKernelGGL((emit_t_kernel<1>), dim3((NCELL + 31) / 32, NB), dim3(320), 0,
                           stream, featT, win, (float*)d_out);
    } else {
        hipMemsetAsync(win, 0xFF, win1, stream);
        hipLaunchKernelGGL((pt_kernel<1>), dim3(PBLK), dim3(256), 0, stream,
                           points, img_feat, (float*)nullptr, l2i, iam, lam, win);
        hipLaunchKernelGGL(emit_kernel, dim3((NCELL + 31) / 32, NB), dim3(256), 0,
                           stream, img_feat, win, (float*)d_out);
    }
}